// Round 6
// baseline (271.521 us; speedup 1.0000x reference)
//
#include <hip/hip_runtime.h>
#include <math.h>

#define NPTS 16384
#define KNB  16
#define D    512
#define FQ_STRIDE 16896  // 33*512, one k-quarter partial plane

// ---------------------------------------------------------------------------
// Closed-form restructure (verified rounds 1-12, absmax 0.0625). With
// S = gather-mean, R = Wres^T + I, M' = (W2c*W1)^T, per-block map
// f' = Cb + S^2 f M' + f R (f0 = 0), tracked in [33,512] coefficient space
// (rows 4k+c = component c of s_k, row 32 = bias):
//   F_1 = Cb33,   F_{t+1} = Cb33 + Shift2(F_t)*M' + F_t*R,   Ecat = F_4
// Final: out = [s0..s7,1] ([N,33]) x Ecat.
// Round 19 (from round-18's 152.6): fstep is still the hopf pace-setter
// (fstep132 block = 512KB of Rm+Mt through one CU's L1 ~ 3.4us vs hop ~1us).
// Two fixes: (a) row-PAIRING — 2 output rows share one tile read (total
// fstep traffic 66 -> 33 MB/dispatch); (b) k-QUARTERS — 256KB/block.
// fstep_g2: 17 row-pairs x 2 j-halves x 4 k-quarters = 136 blocks x 4K
// lines (~1.7us). hopf's hop side -> 8 thr/pt (128 blocks, round-0
// verified onehop8): grid 136+128 = 264, fstep first so the 8 doubled CUs
// get (fstep+hop), not 2 fsteps. Partial-quads: each quarter fp64-
// accumulated, fp32-rounded once; consumers sum 4 (ulp-level). Single
// scheduling round everywhere (in-kernel device barriers cost ~70us on
// 8-XCD MI355X — never again).
// ---------------------------------------------------------------------------

// 1-hop gather-mean, 8 threads/point, 2 neighbors each (ILP), t < 131072
__device__ __forceinline__ void onehop8(int t, const int* __restrict__ knn,
                                        const float4* __restrict__ in,
                                        float4* __restrict__ out) {
  int n = t >> 3, k = t & 7;
  float4 g1 = in[knn[n * KNB + k]];
  float4 g2 = in[knn[n * KNB + k + 8]];
  float ax = g1.x + g2.x, ay = g1.y + g2.y;
  float az = g1.z + g2.z, aw = g1.w + g2.w;
#pragma unroll
  for (int o = 1; o < 8; o <<= 1) {
    ax += __shfl_xor(ax, o, 64); ay += __shfl_xor(ay, o, 64);
    az += __shfl_xor(az, o, 64); aw += __shfl_xor(aw, o, 64);
  }
  if (k == 0) {
    const float r = 1.f / 16.f;
    out[n] = make_float4(ax * r, ay * r, az * r, aw * r);
  }
}

// 1-hop gather-mean, 16 threads/point, 1 neighbor each, t < 262144
__device__ __forceinline__ void onehop16(int t, const int* __restrict__ knn,
                                         const float4* __restrict__ in,
                                         float4* __restrict__ out) {
  int n = t >> 4, k = t & 15;
  float4 g = in[knn[t]];  // knn layout is exactly n*16+k == t
  float ax = g.x, ay = g.y, az = g.z, aw = g.w;
#pragma unroll
  for (int o = 1; o < 16; o <<= 1) {
    ax += __shfl_xor(ax, o, 64); ay += __shfl_xor(ay, o, 64);
    az += __shfl_xor(az, o, 64); aw += __shfl_xor(aw, o, 64);
  }
  if (k == 0) {
    const float r = 1.f / 16.f;
    out[n] = make_float4(ax * r, ay * r, az * r, aw * r);
  }
}

__device__ __forceinline__ float4 red16(float ax, float ay, float az,
                                        float aw) {
#pragma unroll
  for (int o = 1; o < 16; o <<= 1) {
    ax += __shfl_xor(ax, o, 64); ay += __shfl_xor(ay, o, 64);
    az += __shfl_xor(az, o, 64); aw += __shfl_xor(aw, o, 64);
  }
  return make_float4(ax, ay, az, aw);
}

// Horner row-pair k-quarter step, 136 blocks:
// fb -> pair = fb>>3 (rows 2p, 2p+1; p==16 -> row 32 + dummy), sub = fb&7:
// jhalf = sub&1 (256 cols), kq = sub>>1 (128 k). Each thread: 4 cols x 8 k
// x BOTH rows (tile float4 loads shared across rows), acc fp64, LDS reduce
// per row (two phases, shared redm). Output: fp32 partial plane kq (kq 0
// carries +cb). Inputs: previous level as 4 partial planes summed at load.
__device__ __forceinline__ void fstep_g2(
    int fb, int tid, int first, const float* __restrict__ Fq,
    const float* __restrict__ zbuf, const float* __restrict__ Rm,
    const float* __restrict__ Mt, float* __restrict__ Pq) {
  __shared__ float sA[2][128], sB[2][128];
  __shared__ double redm[16][256];
  const int pair = fb >> 3, sub = fb & 7;
  const int jhalf = sub & 1, kq = sub >> 1;
  const int r0 = pair * 2, r1 = r0 + 1;  // r1 == 33 invalid when pair == 16
  const int jbase = jhalf * 256, kbase = kq * 128;
  if (tid < 512) {
    const int quad = tid >> 7, kk = kbase + (tid & 127);
    int r = (quad < 2) ? r0 : r1;
    if (quad & 1)  // shift row: rm(r)
      r = (r >= 8 && r < 32) ? (r - 8) : (r == 32 ? 32 : -1);
    float v = 0.f;
    if (r >= 0 && r <= 32) {
      if (first) {
        if (r < 8)       v = zbuf[r * D + kk];
        else if (r == 32) v = zbuf[8 * D + kk];
      } else {
        const float* p = Fq + (size_t)r * D + kk;
        v = (p[0] + p[FQ_STRIDE]) + (p[2 * FQ_STRIDE] + p[3 * FQ_STRIDE]);
      }
    }
    ((quad & 1) ? sB : sA)[quad >> 1][tid & 127] = v;
  }
  __syncthreads();
  const int q = tid & 63, kc = tid >> 6;   // 64 col-quads x 16 k-chunks of 8
  const int j0 = jbase + q * 4, kl = kc * 8;
  double a00 = 0, a01 = 0, a02 = 0, a03 = 0;
  double a10 = 0, a11 = 0, a12 = 0, a13 = 0;
#pragma unroll
  for (int k = 0; k < 8; ++k) {
    const size_t krow = (size_t)(kbase + kl + k) * D;
    const float4 rv = *(const float4*)(Rm + krow + j0);
    const float4 mv = *(const float4*)(Mt + krow + j0);
    const double aa0 = (double)sA[0][kl + k], bb0 = (double)sB[0][kl + k];
    const double aa1 = (double)sA[1][kl + k], bb1 = (double)sB[1][kl + k];
    a00 += aa0 * (double)rv.x + bb0 * (double)mv.x;
    a01 += aa0 * (double)rv.y + bb0 * (double)mv.y;
    a02 += aa0 * (double)rv.z + bb0 * (double)mv.z;
    a03 += aa0 * (double)rv.w + bb0 * (double)mv.w;
    a10 += aa1 * (double)rv.x + bb1 * (double)mv.x;
    a11 += aa1 * (double)rv.y + bb1 * (double)mv.y;
    a12 += aa1 * (double)rv.z + bb1 * (double)mv.z;
    a13 += aa1 * (double)rv.w + bb1 * (double)mv.w;
  }
  // row 0 reduce
  redm[kc][q * 4 + 0] = a00; redm[kc][q * 4 + 1] = a01;
  redm[kc][q * 4 + 2] = a02; redm[kc][q * 4 + 3] = a03;
  __syncthreads();
  if (tid < 256) {
    double s = 0.0;
#pragma unroll
    for (int u = 0; u < 16; ++u) s += redm[u][tid];
    int j = jbase + tid;
    float cb = 0.f;
    if (kq == 0)
      cb = (r0 < 8) ? zbuf[r0 * D + j] : (r0 == 32 ? zbuf[8 * D + j] : 0.f);
    Pq[(size_t)kq * FQ_STRIDE + r0 * D + j] = (float)(s + (double)cb);
  }
  __syncthreads();
  // row 1 reduce (reuse redm)
  redm[kc][q * 4 + 0] = a10; redm[kc][q * 4 + 1] = a11;
  redm[kc][q * 4 + 2] = a12; redm[kc][q * 4 + 3] = a13;
  __syncthreads();
  if (tid < 256 && r1 < 33) {
    double s = 0.0;
#pragma unroll
    for (int u = 0; u < 16; ++u) s += redm[u][tid];
    int j = jbase + tid;
    float cb = 0.f;
    if (kq == 0)
      cb = (r1 < 8) ? zbuf[r1 * D + j] : 0.f;  // r1 is odd, never 32
    Pq[(size_t)kq * FQ_STRIDE + r1 * D + j] = (float)(s + (double)cb);
  }
}

// ---- L0: knn normalize | geo (16 thr/pt) | pq(z) | Mt | Rm ----
// (verified round-2 form: broadcast/coalesced reads, scattered writes)
__global__ __launch_bounds__(256) void prep_kernel(
    const float* __restrict__ pts, const int* __restrict__ raw,
    const float* __restrict__ w_mlp1, const float* __restrict__ b_mlp1,
    const float* __restrict__ w_lfa1, const float* __restrict__ b_lfa1,
    const float* __restrict__ w_lfa2, const float* __restrict__ b_lfa2,
    const float* __restrict__ w_mlp2, const float* __restrict__ b_mlp2,
    const float* __restrict__ w_res, const float* __restrict__ b_res,
    int* __restrict__ knn_i, float4* __restrict__ sbase,
    float* __restrict__ zbuf, float* __restrict__ Mt,
    float* __restrict__ Rm) {
  // int64 little-endian => odd words are zero high halves; (1/16384)^4 FP risk
  const bool is64 = (raw[1] == 0) && (raw[3] == 0) && (raw[5] == 0) &&
                    (raw[7] == 0);
  const int t = blockIdx.x * 256 + threadIdx.x;  // < 262144 == D*D
  knn_i[t] = is64 ? raw[2 * t] : raw[t];
  {  // geo: 16 threads/point
    int n = t >> 4, k = t & 15;
    int idx = is64 ? raw[2 * (n * KNB + k)] : raw[n * KNB + k];
    float dx = pts[n * 3 + 0] - pts[idx * 3 + 0];
    float dy = pts[n * 3 + 1] - pts[idx * 3 + 1];
    float dz = pts[n * 3 + 2] - pts[idx * 3 + 2];
    float nr = sqrtf(dx * dx + dy * dy + dz * dz);
    float4 s = red16(dx, dy, dz, nr);
    if (k == 0) {
      const float r = 1.f / 16.f;
      sbase[n] = make_float4(s.x * r, s.y * r, s.z * r, s.w * r);
    }
  }
  if (t < 32768) {  // pq: one wave per output column j; fp64 accumulate
    int j = t >> 6, lane = t & 63;
    const float* wrow = w_mlp2 + (size_t)j * D;
    double acc[9];
#pragma unroll
    for (int u = 0; u < 9; ++u) acc[u] = 0.0;
#pragma unroll
    for (int it = 0; it < 8; ++it) {
      int i = lane + 64 * it;
      double w = wrow[i];
      if (i < 256) {
        acc[0] += w * w_lfa2[i * 4 + 0]; acc[1] += w * w_lfa2[i * 4 + 1];
        acc[2] += w * w_lfa2[i * 4 + 2]; acc[3] += w * w_lfa2[i * 4 + 3];
        acc[8] += w * b_lfa2[i];
      } else if (i < 384) {
        int q = i - 256;
        acc[4] += w * w_lfa1[q * 4 + 0]; acc[5] += w * w_lfa1[q * 4 + 1];
        acc[6] += w * w_lfa1[q * 4 + 2]; acc[7] += w * w_lfa1[q * 4 + 3];
        acc[8] += w * b_lfa1[q];
      } else {
        acc[8] += w * b_mlp1[i - 384];
      }
    }
#pragma unroll
    for (int u = 0; u < 9; ++u) {
      double v = acc[u];
#pragma unroll
      for (int o = 32; o > 0; o >>= 1) v += __shfl_down(v, o, 64);
      if (lane == 0) {
        if (u == 8) v += (double)b_mlp2[j] + (double)b_res[j];
        zbuf[u * D + j] = (float)v;
      }
    }
  }
  {  // Mt[a*D+b] = sum_{i<128} w_mlp2[b][384+i]*w_mlp1[i][a]  (fp64 acc)
    int a = t & 511, b = t >> 9;
    const float* wrow = w_mlp2 + (size_t)b * D + 384;
    double s0 = 0.0, s1 = 0.0, s2 = 0.0, s3 = 0.0;
#pragma unroll 8
    for (int i = 0; i < 128; i += 4) {
      s0 += (double)wrow[i + 0] * (double)w_mlp1[(size_t)(i + 0) * D + a];
      s1 += (double)wrow[i + 1] * (double)w_mlp1[(size_t)(i + 1) * D + a];
      s2 += (double)wrow[i + 2] * (double)w_mlp1[(size_t)(i + 2) * D + a];
      s3 += (double)wrow[i + 3] * (double)w_mlp1[(size_t)(i + 3) * D + a];
    }
    Mt[(size_t)a * D + b] = (float)((s0 + s1) + (s2 + s3));
  }
  {  // Rm[i*D+j] = w_res[j][i] + (i==j)
    int i = t & 511, j = t >> 9;
    Rm[(size_t)i * D + j] = w_res[(size_t)j * D + i] + ((i == j) ? 1.0f : 0.0f);
  }
}

// ---- combined: blocks [0,136) fstep_g2, [136,264) 1-hop (8 thr/pt) ----
// fstep first: the 8 doubled-up CUs (blocks 256..263) pair fstep+hop.
__global__ __launch_bounds__(1024, 8) void hopf_kernel(
    const int* __restrict__ knn, const float4* __restrict__ sin,
    float4* __restrict__ sout, const float* __restrict__ zbuf,
    const float* __restrict__ Rm, const float* __restrict__ Mt,
    const float* __restrict__ Fq, float* __restrict__ Pq, int first) {
  const int tid = threadIdx.x;
  if (blockIdx.x < 136) {
    fstep_g2((int)blockIdx.x, tid, first, Fq, zbuf, Rm, Mt, Pq);
  } else {
    onehop8(((int)blockIdx.x - 136) * 1024 + tid, knn, sin, sout);
  }
}

// ---- pure 1-hop: 256 blocks, 16 thr/pt, no LDS ----
__global__ __launch_bounds__(1024, 8) void hop_kernel(
    const int* __restrict__ knn, const float4* __restrict__ sin,
    float4* __restrict__ sout) {
  onehop16(blockIdx.x * 1024 + threadIdx.x, knn, sin, sout);
}

// ---- L4: out[n][:] = [s0..s7,1][n] x (sum of 4 E partials);
//      s7 inline (1-hop from s6) ----
__global__ __launch_bounds__(1024, 4) void out_kernel(
    const int* __restrict__ knn, const float4* __restrict__ sbase,
    const float* __restrict__ Eq, float* __restrict__ outp) {
  const int tid = threadIdx.x;
  const int n0 = blockIdx.x * 64;
  __shared__ float4 s_t[8][64];
  {  // s7 for this block's 64 points: 16 threads/point
    int pt = tid >> 4, k = tid & 15;
    float4 g = sbase[(size_t)6 * NPTS + knn[(n0 + pt) * KNB + k]];
    float4 s = red16(g.x, g.y, g.z, g.w);
    if (k == 0) {
      const float r = 1.f / 16.f;
      s_t[7][pt] = make_float4(s.x * r, s.y * r, s.z * r, s.w * r);
    }
  }
  if (tid < 448) {  // load s0..s6 tiles
    int k = tid / 64, pt = tid & 63;
    s_t[k][pt] = sbase[(size_t)k * NPTS + n0 + pt];
  }
  __syncthreads();
  const int col2 = tid & 255;  // this thread's float2 column
  const int ptg = tid >> 8;    // 0..3
  float2 tab[33];
#pragma unroll
  for (int r = 0; r < 33; ++r) {
    const float* p = Eq + r * D + col2 * 2;
    float2 p0 = *(const float2*)(p);
    float2 p1 = *(const float2*)(p + FQ_STRIDE);
    float2 p2 = *(const float2*)(p + 2 * FQ_STRIDE);
    float2 p3 = *(const float2*)(p + 3 * FQ_STRIDE);
    tab[r] = make_float2((p0.x + p1.x) + (p2.x + p3.x),
                         (p0.y + p1.y) + (p2.y + p3.y));
  }
#pragma unroll
  for (int it = 0; it < 16; ++it) {
    int pt = ptg * 16 + it;
    float2 acc = tab[32];
#pragma unroll
    for (int k = 0; k < 8; ++k) {
      float4 s = s_t[k][pt];  // wave-uniform LDS broadcast
      float2 e0 = tab[4 * k + 0], e1 = tab[4 * k + 1];
      float2 e2 = tab[4 * k + 2], e3 = tab[4 * k + 3];
      acc.x += s.x * e0.x + s.y * e1.x + s.z * e2.x + s.w * e3.x;
      acc.y += s.x * e0.y + s.y * e1.y + s.z * e2.y + s.w * e3.y;
    }
    *(float2*)(outp + (size_t)(n0 + pt) * D + col2 * 2) = acc;
  }
}

extern "C" void kernel_launch(void* const* d_in, const int* in_sizes, int n_in,
                              void* d_out, int out_size, void* d_ws,
                              size_t ws_size, hipStream_t stream) {
  const float* inputs = (const float*)d_in[0];
  const int* knn_raw  = (const int*)d_in[1];
  const float* w_mlp1 = (const float*)d_in[2];
  const float* b_mlp1 = (const float*)d_in[3];
  const float* w_lfa1 = (const float*)d_in[4];
  const float* b_lfa1 = (const float*)d_in[5];
  const float* w_lfa2 = (const float*)d_in[6];
  const float* b_lfa2 = (const float*)d_in[7];
  const float* w_mlp2 = (const float*)d_in[8];
  const float* b_mlp2 = (const float*)d_in[9];
  const float* w_res  = (const float*)d_in[10];
  const float* b_res  = (const float*)d_in[11];
  float* out = (float*)d_out;

  // workspace (floats): ~5.8 MB
  float*  ws    = (float*)d_ws;
  float4* sbase = (float4*)(ws + 0);          // 8 * 16384 float4
  float*  zbuf  = ws + 524288;                // 9 * 512
  float*  F2q   = ws + 528896;                // 4 * 33 * 512 (also Eq)
  float*  F3q   = ws + 596480;                // 4 * 33 * 512
  int*    knn_i = (int*)(ws + 664064);        // 262144 ints
  float*  Mt    = ws + 926208;                // 262144 floats
  float*  Rm    = ws + 1188352;               // 262144 floats (end 1450496)

  prep_kernel<<<1024, 256, 0, stream>>>(inputs, knn_raw, w_mlp1, b_mlp1,
                                        w_lfa1, b_lfa1, w_lfa2, b_lfa2,
                                        w_mlp2, b_mlp2, w_res, b_res,
                                        knn_i, sbase, zbuf, Mt, Rm);
  float4* s0 = (float4*)sbase;
  // H1: s1 = S s0 | fstep1: F2q = step(Cb)
  hopf_kernel<<<264, 1024, 0, stream>>>(knn_i, s0, s0 + NPTS, zbuf, Rm, Mt,
                                        (const float*)nullptr, F2q, 1);
  // H2: s2 = S s1
  hop_kernel<<<256, 1024, 0, stream>>>(knn_i, s0 + NPTS, s0 + 2 * NPTS);
  // H3: s3 = S s2 | fstep2: F3q = step(sum F2q)
  hopf_kernel<<<264, 1024, 0, stream>>>(knn_i, s0 + 2 * NPTS, s0 + 3 * NPTS,
                                        zbuf, Rm, Mt, F2q, F3q, 0);
  // H4: s4 = S s3
  hop_kernel<<<256, 1024, 0, stream>>>(knn_i, s0 + 3 * NPTS, s0 + 4 * NPTS);
  // H5: s5 = S s4 | fstep3: Eq = step(sum F3q)  (aliases F2q)
  hopf_kernel<<<264, 1024, 0, stream>>>(knn_i, s0 + 4 * NPTS, s0 + 5 * NPTS,
                                        zbuf, Rm, Mt, F3q, F2q, 0);
  // H6: s6 = S s5
  hop_kernel<<<256, 1024, 0, stream>>>(knn_i, s0 + 5 * NPTS, s0 + 6 * NPTS);
  // L4: out (s7 inline), Ecat = sum of Eq partials
  out_kernel<<<256, 1024, 0, stream>>>(knn_i, sbase, F2q, out);
}

// Round 9
// 149.910 us; speedup vs baseline: 1.8112x; 1.8112x over previous
//
#include <hip/hip_runtime.h>
#include <math.h>

#define NPTS 16384
#define KNB  16
#define D    512

// ---------------------------------------------------------------------------
// Closed-form restructure (verified rounds 1-12, absmax 0.0625). With
// S = gather-mean, R = Wres^T + I, M' = (W2c*W1)^T, per-block map
// f' = Cb + S^2 f M' + f R (f0 = 0), tracked in [33,512] coefficient space
// (rows 4k+c = component c of s_k, row 32 = bias):
//   F_1 = Cb33,   F_{t+1} = Cb33 + Shift2(F_t)*M' + F_t*R,   Ecat = F_4
// Final: out = [s0..s7,1] ([N,33]) x Ecat.
// Round 22: EXACT re-submit of the round-5-verified source (152.6us).
// Rounds 7/8 failed at container level on a reorder variant; re-running
// the known-good bytes disambiguates infra vs source and re-anchors the
// baseline. Structure: 8-dispatch chain; fstep132 half-steps (132 blocks,
// 512KB Rm+Mt each) fused into hopf dispatches at blocks 256..387; hops
// 16 thr/pt. Partial-pair outputs (Pa,Pb) summed by consumers. Single
// scheduling round everywhere (in-kernel device barriers cost ~70us on
// 8-XCD MI355X — never again).
// ---------------------------------------------------------------------------

// 1-hop gather-mean, 16 threads/point, 1 neighbor each, t < 262144
__device__ __forceinline__ void onehop16(int t, const int* __restrict__ knn,
                                         const float4* __restrict__ in,
                                         float4* __restrict__ out) {
  int n = t >> 4, k = t & 15;
  float4 g = in[knn[t]];  // knn layout is exactly n*16+k == t
  float ax = g.x, ay = g.y, az = g.z, aw = g.w;
#pragma unroll
  for (int o = 1; o < 16; o <<= 1) {
    ax += __shfl_xor(ax, o, 64); ay += __shfl_xor(ay, o, 64);
    az += __shfl_xor(az, o, 64); aw += __shfl_xor(aw, o, 64);
  }
  if (k == 0) {
    const float r = 1.f / 16.f;
    out[n] = make_float4(ax * r, ay * r, az * r, aw * r);
  }
}

__device__ __forceinline__ float4 red16(float ax, float ay, float az,
                                        float aw) {
#pragma unroll
  for (int o = 1; o < 16; o <<= 1) {
    ax += __shfl_xor(ax, o, 64); ay += __shfl_xor(ay, o, 64);
    az += __shfl_xor(az, o, 64); aw += __shfl_xor(aw, o, 64);
  }
  return make_float4(ax, ay, az, aw);
}

// One Horner half-step, 132 blocks: fb2 -> khalf = fb2&1, fb = fb2>>1,
// row r = fb>>1, cols jbase..jbase+255 (jbase = (fb&1)*256), k-range
// khalf*256..+256. Threads: 64 col-quads x 16 k-chunks of 16. float4 loads
// of Rm/Mt, acc[4] fp64/thread, LDS reduce. Inputs: previous level as a
// partial PAIR (Fpa+Fpb summed at load); output: this half's fp32 partial
// (khalf 0 carries the +cb term). Halves per-CU L1 traffic vs fstep66.
__device__ __forceinline__ void fstep132(
    int fb2, int tid, int first, const float* __restrict__ Fpa,
    const float* __restrict__ Fpb, const float* __restrict__ zbuf,
    const float* __restrict__ Rm, const float* __restrict__ Mt,
    float* __restrict__ Pa, float* __restrict__ Pb) {
  __shared__ float sA[256], sB[256];
  __shared__ double redm[16][256];
  const int khalf = fb2 & 1, fb = fb2 >> 1;
  const int r = fb >> 1, jbase = (fb & 1) * 256;
  const int rm = (r >= 8 && r < 32) ? (r - 8) : (r == 32 ? 32 : -1);
  const int kbase = khalf * 256;
  if (tid < 256) {
    int kk = kbase + tid;
    sA[tid] = first
        ? ((r < 8) ? zbuf[r * D + kk] : (r == 32 ? zbuf[8 * D + kk] : 0.f))
        : (Fpa[r * D + kk] + Fpb[r * D + kk]);
  } else if (tid < 512) {
    int kk = kbase + (tid - 256);
    float v = 0.f;
    if (rm >= 0)
      v = first ? ((rm < 8) ? zbuf[rm * D + kk]
                            : (rm == 32 ? zbuf[8 * D + kk] : 0.f))
                : (Fpa[rm * D + kk] + Fpb[rm * D + kk]);
    sB[tid - 256] = v;
  }
  __syncthreads();
  const int q = tid & 63, kc = tid >> 6;   // col-quad, k-chunk (16 x 16)
  const int j0 = jbase + q * 4, kl = kc * 16;
  double a0 = 0, a1 = 0, a2 = 0, a3 = 0;
#pragma unroll 2
  for (int k = 0; k < 16; ++k) {
    const size_t krow = (size_t)(kbase + kl + k) * D;
    const float4 rv = *(const float4*)(Rm + krow + j0);
    const float4 mv = *(const float4*)(Mt + krow + j0);
    const double a = (double)sA[kl + k], b = (double)sB[kl + k];
    a0 += a * (double)rv.x + b * (double)mv.x;
    a1 += a * (double)rv.y + b * (double)mv.y;
    a2 += a * (double)rv.z + b * (double)mv.z;
    a3 += a * (double)rv.w + b * (double)mv.w;
  }
  redm[kc][q * 4 + 0] = a0; redm[kc][q * 4 + 1] = a1;
  redm[kc][q * 4 + 2] = a2; redm[kc][q * 4 + 3] = a3;
  __syncthreads();
  if (tid < 256) {
    double s = 0.0;
#pragma unroll
    for (int u = 0; u < 16; ++u) s += redm[u][tid];
    int j = jbase + tid;
    float cb = 0.f;
    if (khalf == 0)
      cb = (r < 8) ? zbuf[r * D + j] : (r == 32 ? zbuf[8 * D + j] : 0.f);
    (khalf ? Pb : Pa)[r * D + j] = (float)(s + (double)cb);
  }
}

// ---- L0: knn normalize | geo (16 thr/pt) | pq(z) | Mt | Rm ----
// (verified round-2 form: broadcast/coalesced reads, scattered writes)
__global__ __launch_bounds__(256) void prep_kernel(
    const float* __restrict__ pts, const int* __restrict__ raw,
    const float* __restrict__ w_mlp1, const float* __restrict__ b_mlp1,
    const float* __restrict__ w_lfa1, const float* __restrict__ b_lfa1,
    const float* __restrict__ w_lfa2, const float* __restrict__ b_lfa2,
    const float* __restrict__ w_mlp2, const float* __restrict__ b_mlp2,
    const float* __restrict__ w_res, const float* __restrict__ b_res,
    int* __restrict__ knn_i, float4* __restrict__ sbase,
    float* __restrict__ zbuf, float* __restrict__ Mt,
    float* __restrict__ Rm) {
  // int64 little-endian => odd words are zero high halves; (1/16384)^4 FP risk
  const bool is64 = (raw[1] == 0) && (raw[3] == 0) && (raw[5] == 0) &&
                    (raw[7] == 0);
  const int t = blockIdx.x * 256 + threadIdx.x;  // < 262144 == D*D
  knn_i[t] = is64 ? raw[2 * t] : raw[t];
  {  // geo: 16 threads/point
    int n = t >> 4, k = t & 15;
    int idx = is64 ? raw[2 * (n * KNB + k)] : raw[n * KNB + k];
    float dx = pts[n * 3 + 0] - pts[idx * 3 + 0];
    float dy = pts[n * 3 + 1] - pts[idx * 3 + 1];
    float dz = pts[n * 3 + 2] - pts[idx * 3 + 2];
    float nr = sqrtf(dx * dx + dy * dy + dz * dz);
    float4 s = red16(dx, dy, dz, nr);
    if (k == 0) {
      const float r = 1.f / 16.f;
      sbase[n] = make_float4(s.x * r, s.y * r, s.z * r, s.w * r);
    }
  }
  if (t < 32768) {  // pq: one wave per output column j; fp64 accumulate
    int j = t >> 6, lane = t & 63;
    const float* wrow = w_mlp2 + (size_t)j * D;
    double acc[9];
#pragma unroll
    for (int u = 0; u < 9; ++u) acc[u] = 0.0;
#pragma unroll
    for (int it = 0; it < 8; ++it) {
      int i = lane + 64 * it;
      double w = wrow[i];
      if (i < 256) {
        acc[0] += w * w_lfa2[i * 4 + 0]; acc[1] += w * w_lfa2[i * 4 + 1];
        acc[2] += w * w_lfa2[i * 4 + 2]; acc[3] += w * w_lfa2[i * 4 + 3];
        acc[8] += w * b_lfa2[i];
      } else if (i < 384) {
        int q = i - 256;
        acc[4] += w * w_lfa1[q * 4 + 0]; acc[5] += w * w_lfa1[q * 4 + 1];
        acc[6] += w * w_lfa1[q * 4 + 2]; acc[7] += w * w_lfa1[q * 4 + 3];
        acc[8] += w * b_lfa1[q];
      } else {
        acc[8] += w * b_mlp1[i - 384];
      }
    }
#pragma unroll
    for (int u = 0; u < 9; ++u) {
      double v = acc[u];
#pragma unroll
      for (int o = 32; o > 0; o >>= 1) v += __shfl_down(v, o, 64);
      if (lane == 0) {
        if (u == 8) v += (double)b_mlp2[j] + (double)b_res[j];
        zbuf[u * D + j] = (float)v;
      }
    }
  }
  {  // Mt[a*D+b] = sum_{i<128} w_mlp2[b][384+i]*w_mlp1[i][a]  (fp64 acc)
    int a = t & 511, b = t >> 9;
    const float* wrow = w_mlp2 + (size_t)b * D + 384;
    double s0 = 0.0, s1 = 0.0, s2 = 0.0, s3 = 0.0;
#pragma unroll 8
    for (int i = 0; i < 128; i += 4) {
      s0 += (double)wrow[i + 0] * (double)w_mlp1[(size_t)(i + 0) * D + a];
      s1 += (double)wrow[i + 1] * (double)w_mlp1[(size_t)(i + 1) * D + a];
      s2 += (double)wrow[i + 2] * (double)w_mlp1[(size_t)(i + 2) * D + a];
      s3 += (double)wrow[i + 3] * (double)w_mlp1[(size_t)(i + 3) * D + a];
    }
    Mt[(size_t)a * D + b] = (float)((s0 + s1) + (s2 + s3));
  }
  {  // Rm[i*D+j] = w_res[j][i] + (i==j)
    int i = t & 511, j = t >> 9;
    Rm[(size_t)i * D + j] = w_res[(size_t)j * D + i] + ((i == j) ? 1.0f : 0.0f);
  }
}

// ---- combined: blocks [0,256) 1-hop (16 thr/pt), [256,388) fstep132 ----
__global__ __launch_bounds__(1024, 8) void hopf_kernel(
    const int* __restrict__ knn, const float4* __restrict__ sin,
    float4* __restrict__ sout, const float* __restrict__ zbuf,
    const float* __restrict__ Rm, const float* __restrict__ Mt,
    const float* __restrict__ Fpa, const float* __restrict__ Fpb,
    float* __restrict__ Pa, float* __restrict__ Pb, int first) {
  const int tid = threadIdx.x;
  if (blockIdx.x < 256) {
    onehop16(blockIdx.x * 1024 + tid, knn, sin, sout);
  } else {
    fstep132((int)blockIdx.x - 256, tid, first, Fpa, Fpb, zbuf, Rm, Mt,
             Pa, Pb);
  }
}

// ---- pure 1-hop: 256 blocks, 16 thr/pt, no LDS ----
__global__ __launch_bounds__(1024, 8) void hop_kernel(
    const int* __restrict__ knn, const float4* __restrict__ sin,
    float4* __restrict__ sout) {
  onehop16(blockIdx.x * 1024 + threadIdx.x, knn, sin, sout);
}

// ---- L4: out[n][:] = [s0..s7,1][n] x (Ea+Eb); s7 inline (1-hop from s6) ----
__global__ __launch_bounds__(1024, 4) void out_kernel(
    const int* __restrict__ knn, const float4* __restrict__ sbase,
    const float* __restrict__ Ea, const float* __restrict__ Eb,
    float* __restrict__ outp) {
  const int tid = threadIdx.x;
  const int n0 = blockIdx.x * 64;
  __shared__ float4 s_t[8][64];
  {  // s7 for this block's 64 points: 16 threads/point
    int pt = tid >> 4, k = tid & 15;
    float4 g = sbase[(size_t)6 * NPTS + knn[(n0 + pt) * KNB + k]];
    float4 s = red16(g.x, g.y, g.z, g.w);
    if (k == 0) {
      const float r = 1.f / 16.f;
      s_t[7][pt] = make_float4(s.x * r, s.y * r, s.z * r, s.w * r);
    }
  }
  if (tid < 448) {  // load s0..s6 tiles
    int k = tid / 64, pt = tid & 63;
    s_t[k][pt] = sbase[(size_t)k * NPTS + n0 + pt];
  }
  __syncthreads();
  const int col2 = tid & 255;  // this thread's float2 column
  const int ptg = tid >> 8;    // 0..3
  float2 tab[33];
#pragma unroll
  for (int r = 0; r < 33; ++r) {
    float2 pa = *(const float2*)(Ea + r * D + col2 * 2);
    float2 pb = *(const float2*)(Eb + r * D + col2 * 2);
    tab[r] = make_float2(pa.x + pb.x, pa.y + pb.y);
  }
#pragma unroll
  for (int it = 0; it < 16; ++it) {
    int pt = ptg * 16 + it;
    float2 acc = tab[32];
#pragma unroll
    for (int k = 0; k < 8; ++k) {
      float4 s = s_t[k][pt];  // wave-uniform LDS broadcast
      float2 e0 = tab[4 * k + 0], e1 = tab[4 * k + 1];
      float2 e2 = tab[4 * k + 2], e3 = tab[4 * k + 3];
      acc.x += s.x * e0.x + s.y * e1.x + s.z * e2.x + s.w * e3.x;
      acc.y += s.x * e0.y + s.y * e1.y + s.z * e2.y + s.w * e3.y;
    }
    *(float2*)(outp + (size_t)(n0 + pt) * D + col2 * 2) = acc;
  }
}

extern "C" void kernel_launch(void* const* d_in, const int* in_sizes, int n_in,
                              void* d_out, int out_size, void* d_ws,
                              size_t ws_size, hipStream_t stream) {
  const float* inputs = (const float*)d_in[0];
  const int* knn_raw  = (const int*)d_in[1];
  const float* w_mlp1 = (const float*)d_in[2];
  const float* b_mlp1 = (const float*)d_in[3];
  const float* w_lfa1 = (const float*)d_in[4];
  const float* b_lfa1 = (const float*)d_in[5];
  const float* w_lfa2 = (const float*)d_in[6];
  const float* b_lfa2 = (const float*)d_in[7];
  const float* w_mlp2 = (const float*)d_in[8];
  const float* b_mlp2 = (const float*)d_in[9];
  const float* w_res  = (const float*)d_in[10];
  const float* b_res  = (const float*)d_in[11];
  float* out = (float*)d_out;

  // workspace (floats): ~5.5 MB
  float*  ws    = (float*)d_ws;
  float4* sbase = (float4*)(ws + 0);          // 8 * 16384 float4
  float*  zbuf  = ws + 524288;                // 9 * 512
  float*  F2a   = ws + 528896;                // 33 * 512 (also Ea)
  float*  F2b   = ws + 545792;                // 33 * 512 (also Eb)
  float*  F3a   = ws + 562688;                // 33 * 512
  float*  F3b   = ws + 579584;                // 33 * 512
  int*    knn_i = (int*)(ws + 596480);        // 262144 ints
  float*  Mt    = ws + 858624;                // 262144 floats
  float*  Rm    = ws + 1120768;               // 262144 floats (end 1382912)

  prep_kernel<<<1024, 256, 0, stream>>>(inputs, knn_raw, w_mlp1, b_mlp1,
                                        w_lfa1, b_lfa1, w_lfa2, b_lfa2,
                                        w_mlp2, b_mlp2, w_res, b_res,
                                        knn_i, sbase, zbuf, Mt, Rm);
  float4* s0 = (float4*)sbase;
  // H1: s1 = S s0 | fstep1: (F2a,F2b) = step(Cb)
  hopf_kernel<<<388, 1024, 0, stream>>>(knn_i, s0, s0 + NPTS, zbuf, Rm, Mt,
                                        (const float*)nullptr,
                                        (const float*)nullptr, F2a, F2b, 1);
  // H2: s2 = S s1
  hop_kernel<<<256, 1024, 0, stream>>>(knn_i, s0 + NPTS, s0 + 2 * NPTS);
  // H3: s3 = S s2 | fstep2: (F3a,F3b) = step(F2a+F2b)
  hopf_kernel<<<388, 1024, 0, stream>>>(knn_i, s0 + 2 * NPTS, s0 + 3 * NPTS,
                                        zbuf, Rm, Mt, F2a, F2b, F3a, F3b, 0);
  // H4: s4 = S s3
  hop_kernel<<<256, 1024, 0, stream>>>(knn_i, s0 + 3 * NPTS, s0 + 4 * NPTS);
  // H5: s5 = S s4 | fstep3: (Ea,Eb) = step(F3a+F3b)  (aliases F2a,F2b)
  hopf_kernel<<<388, 1024, 0, stream>>>(knn_i, s0 + 4 * NPTS, s0 + 5 * NPTS,
                                        zbuf, Rm, Mt, F3a, F3b, F2a, F2b, 0);
  // H6: s6 = S s5
  hop_kernel<<<256, 1024, 0, stream>>>(knn_i, s0 + 5 * NPTS, s0 + 6 * NPTS);
  // L4: out (s7 inline), Ecat = Ea + Eb
  out_kernel<<<256, 1024, 0, stream>>>(knn_i, sbase, F2a, F2b, out);
}